// Round 5
// baseline (4384.007 us; speedup 1.0000x reference)
//
#include <hip/hip_runtime.h>
#include <hip/hip_bf16.h>
#include <math.h>

#define STEPS 2048
#define BATCH 512

typedef __attribute__((ext_vector_type(8))) short short8;
typedef __attribute__((ext_vector_type(4))) short short4v;
typedef __attribute__((ext_vector_type(2))) short short2v;
typedef __attribute__((ext_vector_type(4))) float f32x4;

__device__ __forceinline__ short f2bf(float f) {
    union { float f; unsigned u; } v; v.f = f;
    unsigned u = v.u;
    return (short)((u + 0x7FFFu + ((u >> 16) & 1u)) >> 16);  // RNE
}
__device__ __forceinline__ unsigned f2bfu(float f) {
    return (unsigned)(unsigned short)f2bf(f);
}
__device__ __forceinline__ short2v pk2(float a, float b) {
    __hip_bfloat162 h = __float22bfloat162_rn(make_float2(a, b));
    union { __hip_bfloat162 h; short2v s; } u; u.h = h; return u.s;
}

// ---------------------------------------------------------------------------
// baseflow[b] = 25th percentile (linear interp) of flow[:, b]
// ---------------------------------------------------------------------------
__global__ __launch_bounds__(256) void baseflow_kernel(
    const float* __restrict__ hyd, float* __restrict__ bf)
{
    __shared__ float arr[STEPS];
    const int b = blockIdx.x;
    const int tid = threadIdx.x;
    for (int t = tid; t < STEPS; t += 256)
        arr[t] = hyd[(size_t)(t * BATCH + b) * 17];
    __syncthreads();
    for (int k = 2; k <= STEPS; k <<= 1) {
        for (int j = k >> 1; j > 0; j >>= 1) {
            for (int i = tid; i < STEPS; i += 256) {
                int ixj = i ^ j;
                if (ixj > i) {
                    float a = arr[i], c = arr[ixj];
                    bool up = ((i & k) == 0);
                    if (up ? (a > c) : (a < c)) { arr[i] = c; arr[ixj] = a; }
                }
            }
            __syncthreads();
        }
    }
    if (tid == 0) bf[b] = arr[511] + 0.75f * (arr[512] - arr[511]);
}

// ---------------------------------------------------------------------------
// 512 blocks x 256 threads (4 waves), ONE batch column per block
// -> 2 blocks/CU for cross-block latency hiding.
//  - x_t pre-staged in LDS ring (16 steps/refill)
//  - three MFMA phases (L0/L1/heads), weights in register A-frags
//  - tail: octet-distributed (lane j=lane&7 owns store j), shfl_xor sums,
//    12 b32 LDS reads/lane (broadcast, conflict-free) instead of 23 b128
//  - stores fragment (spack) rebuilt per-wave by 5 shuffles onto lanes
//    j8==0 (lane 32 = the cg==2,cn==0 B-frag lane) -> no 4th barrier
//  - rain read pre-B3 so the next group's refill can't race it
// ---------------------------------------------------------------------------
__global__ __launch_bounds__(256, 2) void hyd_step_kernel(
    const float* __restrict__ hyd,
    const float* __restrict__ W0,  const float* __restrict__ b0,
    const float* __restrict__ W1,  const float* __restrict__ b1,
    const float* __restrict__ Win, const float* __restrict__ bin,
    const float* __restrict__ Wout,const float* __restrict__ bout,
    const float* __restrict__ baseflow,
    float* __restrict__ out)
{
    __shared__ __align__(16) short h1F[256 * 8];
    __shared__ __align__(16) short h2F[256 * 8];
    __shared__ __align__(16) short ringX[16 * 2 * 8];  // [slot][g2][j]
    __shared__ float ringR[16];                        // rain (hyd[...,1])
    __shared__ __align__(16) float hb[96];             // m<9: exp(logit); else sigmoid

    const int tid  = threadIdx.x;
    const int b    = blockIdx.x;
    const int lane = tid & 63;
    const int wv   = tid >> 6;
    const int cn   = lane & 15;
    const int cg   = lane >> 4;
    const int j8   = lane & 7;

    for (int i = tid; i < 256 * 8; i += 256) { h1F[i] = 0; h2F[i] = 0; }

    // ---- weight A-fragments + bias C-inits (one-time) ----
    short8 a0[2]; f32x4 c0[2];
    short8 a1[2][4]; f32x4 c1[2];
    short8 ah[2][4]; f32x4 ch[2];
    #pragma unroll
    for (int i = 0; i < 2; ++i) {
        const int mt = 2 * wv + i;
        const int row = mt * 16 + cn;
        #pragma unroll
        for (int j = 0; j < 8; ++j) {
            int k = cg * 8 + j;
            a0[i][j] = (k < 24) ? f2bf(W0[row * 24 + k]) : (short)0;
        }
        #pragma unroll
        for (int kt = 0; kt < 4; ++kt)
            #pragma unroll
            for (int j = 0; j < 8; ++j)
                a1[i][kt][j] = f2bf(W1[row * 128 + kt * 32 + cg * 8 + j]);
        #pragma unroll
        for (int r = 0; r < 4; ++r) {
            int m = mt * 16 + cg * 4 + r;
            c0[i][r] = b0[m];
            c1[i][r] = b1[m];
        }
    }
    const int nht = (wv < 2) ? 2 : 1;
    int htile[2];
    htile[0] = (wv < 2) ? 2 * wv : 4 + (wv - 2);
    htile[1] = (wv < 2) ? 2 * wv + 1 : htile[0];
    #pragma unroll
    for (int i = 0; i < 2; ++i) {
        const int ht = htile[i];
        const int row = ht * 16 + cn;
        #pragma unroll
        for (int kt = 0; kt < 4; ++kt)
            #pragma unroll
            for (int j = 0; j < 8; ++j) {
                int k = kt * 32 + cg * 8 + j;
                float w = 0.f;
                if (row < 9)       w = Win[row * 128 + k];
                else if (row < 89) w = Wout[(row - 9) * 128 + k];
                ah[i][kt][j] = f2bf(w);
            }
        #pragma unroll
        for (int r = 0; r < 4; ++r) {
            int m = ht * 16 + cg * 4 + r;
            float bb = 0.f;
            if (m < 9)       bb = bin[m];
            else if (m < 89) bb = bout[m - 9];
            ch[i][r] = bb;
        }
    }

    // ---- recurrent state: lane j8 owns store j8 (octet-redundant) ----
    float sj = (j8 == 1) ? 1.f : 0.f;
    const float bfv = baseflow[b];
    // spack = bf16(0.01*stores) packed: (s0,s1),(s2,s3),(s4,s5),(s6,s7)
    unsigned sp0 = (f2bfu(0.01f) << 16);  // (0.0, 0.01)
    unsigned sp1 = 0, sp2 = 0, sp3 = 0;

    for (int tb = 0; tb < STEPS; tb += 16) {
        // ---- ring refill: 16 steps of x (bf16 frag layout) + rain ----
        if (tid < 32) {
            const int tp = tid >> 1, g2 = tid & 1;
            const float* p = hyd + ((size_t)(tb + tp) * BATCH + b) * 17 + 1 + g2 * 8;
            float v0 = p[0], v1 = p[1], v2 = p[2], v3 = p[3];
            float v4 = p[4], v5 = p[5], v6 = p[6], v7 = p[7];
            short8 w;
            short2v q0 = pk2(v0, v1), q1 = pk2(v2, v3), q2 = pk2(v4, v5), q3 = pk2(v6, v7);
            w[0] = q0[0]; w[1] = q0[1]; w[2] = q1[0]; w[3] = q1[1];
            w[4] = q2[0]; w[5] = q2[1]; w[6] = q3[0]; w[7] = q3[1];
            *(short8*)&ringX[(tp * 2 + g2) * 8] = w;
        } else if (tid < 48) {
            const int tp = tid - 32;
            // rain = x[:,:,0] = hyd[...,1] (index 0 is flow!)
            ringR[tp] = hyd[((size_t)(tb + tp) * BATCH + b) * 17 + 1];
        }
        __syncthreads();   // refill published to all waves

        for (int tt = 0; tt < 16; ++tt) {
            const int t = tb + tt;

            // === L0: h1 = relu(W0 @ [x, 0.01*stores] + b0) ===
            short8 bfrag = (short8)0;
            if (cg < 2) {
                if (cn == 0) bfrag = *(const short8*)&ringX[(tt * 2 + cg) * 8];
            } else if (cg == 2) {
                union { unsigned u[4]; short8 s; } su;
                su.u[0] = sp0; su.u[1] = sp1; su.u[2] = sp2; su.u[3] = sp3;
                bfrag = su.s;   // only lane 32 (cn==0) feeds column 0
            }
            #pragma unroll
            for (int i = 0; i < 2; ++i) {
                f32x4 acc = __builtin_amdgcn_mfma_f32_16x16x32_bf16(a0[i], bfrag, c0[i], 0, 0, 0);
                if (cn == 0) {
                    int m0 = (2 * wv + i) * 16 + cg * 4;
                    short4v p;
                    short2v pa = pk2(fmaxf(acc[0], 0.f), fmaxf(acc[1], 0.f));
                    short2v pb = pk2(fmaxf(acc[2], 0.f), fmaxf(acc[3], 0.f));
                    p[0] = pa[0]; p[1] = pa[1]; p[2] = pb[0]; p[3] = pb[1];
                    *(short4v*)&h1F[((m0 >> 3) * 16 + 0) * 8 + (m0 & 7)] = p;
                }
            }
            __syncthreads();   // B1

            // === L1: h2 = relu(W1 @ h1 + b1) ===
            short8 bf1[4];
            #pragma unroll
            for (int kt = 0; kt < 4; ++kt)
                bf1[kt] = *(const short8*)&h1F[(kt * 64 + lane) * 8];
            #pragma unroll
            for (int i = 0; i < 2; ++i) {
                f32x4 acc = c1[i];
                #pragma unroll
                for (int kt = 0; kt < 4; ++kt)
                    acc = __builtin_amdgcn_mfma_f32_16x16x32_bf16(a1[i][kt], bf1[kt], acc, 0, 0, 0);
                if (cn == 0) {
                    int m0 = (2 * wv + i) * 16 + cg * 4;
                    short4v p;
                    short2v pa = pk2(fmaxf(acc[0], 0.f), fmaxf(acc[1], 0.f));
                    short2v pb = pk2(fmaxf(acc[2], 0.f), fmaxf(acc[3], 0.f));
                    p[0] = pa[0]; p[1] = pa[1]; p[2] = pb[0]; p[3] = pb[1];
                    *(short4v*)&h2F[((m0 >> 3) * 16 + 0) * 8 + (m0 & 7)] = p;
                }
            }
            __syncthreads();   // B2

            // rain for this step — read BEFORE B3 so the next group's
            // refill (which happens after B3(15)+tail) can never race it
            const float rain = ringR[tt];

            // === heads: exp(logits) m<9, sigmoid(gates) m>=9 ===
            short8 bf2[4];
            #pragma unroll
            for (int kt = 0; kt < 4; ++kt)
                bf2[kt] = *(const short8*)&h2F[(kt * 64 + lane) * 8];
            #pragma unroll
            for (int i = 0; i < 2; ++i) {
                if (i < nht) {
                    f32x4 acc = ch[i];
                    #pragma unroll
                    for (int kt = 0; kt < 4; ++kt)
                        acc = __builtin_amdgcn_mfma_f32_16x16x32_bf16(ah[i][kt], bf2[kt], acc, 0, 0, 0);
                    if (cn == 0) {
                        const int ht = htile[i];
                        float4 o;
                        #pragma unroll
                        for (int r = 0; r < 4; ++r) {
                            int m = ht * 16 + cg * 4 + r;
                            float v = acc[r];
                            bool isl = (m < 9);
                            float em = __expf(isl ? v : -v);
                            ((float*)&o)[r] = isl ? em : __builtin_amdgcn_rcpf(1.f + em);
                        }
                        *(float4*)&hb[ht * 16 + cg * 4] = o;
                    }
                }
            }
            __syncthreads();   // B3

            // === tail: octet-distributed, every lane runs it (j = j8) ===
            {
                float ej  = hb[1 + j8];          // softmax numerator for store j
                float e0  = hb[0];               // a[0] numerator (discarded slot)
                float Bd[8];
                #pragma unroll
                for (int d = 0; d < 8; ++d) Bd[d] = hb[9 + 8 * d + j8];
                float esc = hb[73 + j8];
                float bfl = hb[81 + j8];

                float den = ej;
                den += __shfl_xor(den, 1, 8);
                den += __shfl_xor(den, 2, 8);
                den += __shfl_xor(den, 4, 8);
                den += e0;
                float rr = rain * __builtin_amdgcn_rcpf(den);
                sj += ej * rr;

                #pragma unroll
                for (int d = 0; d < 8; ++d) {
                    float fb = Bd[d] * sj;
                    float fs = fb;
                    fs += __shfl_xor(fs, 1, 8);
                    fs += __shfl_xor(fs, 2, 8);
                    fs += __shfl_xor(fs, 4, 8);
                    sj -= fb;
                    if (j8 == d) sj += fs;
                }
                sj -= esc * sj;                      // escape
                float fd = bfl * sj;                 // flow
                float fsum = fd;
                fsum += __shfl_xor(fsum, 1, 8);
                fsum += __shfl_xor(fsum, 2, 8);
                fsum += __shfl_xor(fsum, 4, 8);
                sj -= fd;
                if (t == 0) {
                    float bflS = __shfl(bfl, 2, 8);  // b_flow[SLOW=2]
                    if (j8 == 2) sj = bfv / fmaxf(bflS, 1e-5f);
                }
                if (tid == 0) out[(size_t)t * BATCH + b] = fsum;

                // spack gather onto lanes j8==0 (incl. lane 32): 5 shuffles
                unsigned myb = f2bfu(0.01f * sj);
                unsigned prt = (unsigned)__shfl_xor((int)myb, 1, 8);
                unsigned pair = (myb & 0xFFFFu) | (prt << 16);   // (s_j, s_j^1) on even j
                sp0 = pair;
                sp1 = (unsigned)__shfl_xor((int)pair, 2, 8);     // (s2,s3) at j=0
                sp2 = (unsigned)__shfl_xor((int)pair, 4, 8);     // (s4,s5) at j=0
                sp3 = (unsigned)__shfl_xor((int)sp1, 4, 8);      // (s6,s7) at j=0
            }
            // no 4th barrier: spack is per-wave register state; h1F(t+1)
            // writes are ordered after all h1F(t) reads by B2(t)/B3(t)
        }
    }
}

// ---------------------------------------------------------------------------
extern "C" void kernel_launch(void* const* d_in, const int* in_sizes, int n_in,
                              void* d_out, int out_size, void* d_ws, size_t ws_size,
                              hipStream_t stream)
{
    const float* hyd  = (const float*)d_in[0];
    const float* W0   = (const float*)d_in[1];
    const float* b0   = (const float*)d_in[2];
    const float* W1   = (const float*)d_in[3];
    const float* b1   = (const float*)d_in[4];
    const float* Win  = (const float*)d_in[5];
    const float* bin  = (const float*)d_in[6];
    const float* Wout = (const float*)d_in[7];
    const float* bout = (const float*)d_in[8];
    float* out = (float*)d_out;
    float* bf  = (float*)d_ws;

    baseflow_kernel<<<BATCH, 256, 0, stream>>>(hyd, bf);
    hyd_step_kernel<<<BATCH, 256, 0, stream>>>(
        hyd, W0, b0, W1, b1, Win, bin, Wout, bout, bf, out);
}